// Round 7
// baseline (314.352 us; speedup 1.0000x reference)
//
#include <hip/hip_runtime.h>
#include <hip/hip_bf16.h>

typedef float f32x4 __attribute__((ext_vector_type(4)));
typedef short short8 __attribute__((ext_vector_type(8)));

#define LDH 7168
#define MFMA16(d, x, y) d = __builtin_amdgcn_mfma_f32_16x16x32_bf16(x, y, d, 0, 0, 0)

__device__ __forceinline__ void async_ld16(const void* g, void* l) {
  __builtin_amdgcn_global_load_lds(
      (const __attribute__((address_space(1))) unsigned int*)g,
      (__attribute__((address_space(3))) unsigned int*)l, 16, 0, 0);
}

__device__ __forceinline__ float bf2f(unsigned short u) {
  union { unsigned int i; float f; } c; c.i = ((unsigned int)u) << 16; return c.f;
}

// ---------------- decode Win: (7168,1024) bf16
__global__ __launch_bounds__(256) void decode_win_k(const float* __restrict__ cb,
                                                    const int* __restrict__ idx,
                                                    __hip_bfloat16* __restrict__ Win) {
  const int o = blockIdx.x;
  const int cluster = o >> 6;
  #pragma unroll
  for (int ei = 0; ei < 4; ++ei) {
    const int e = ei * 256 + threadIdx.x;
    const int c = e >> 6, s = e & 63;
    const int k0 = idx[(0 * 7168 + o) * 16 + c];
    const int k1 = idx[(1 * 7168 + o) * 16 + c];
    const float v = cb[((((size_t)0 * 112 + cluster) * 16 + c) * 64 + k0) * 64 + s]
                  + cb[((((size_t)1 * 112 + cluster) * 16 + c) * 64 + k1) * 64 + s];
    Win[(size_t)o * 1024 + e] = __float2bfloat16(v);
  }
}

// ---------------- decode Weff: (1024,5120) bf16 = Wout[o] + Wout[o+1024], summed over R
__global__ __launch_bounds__(256) void decode_weff_k(const float* __restrict__ cb,
                                                     const int* __restrict__ idx,
                                                     __hip_bfloat16* __restrict__ W) {
  const int o = blockIdx.x;          // 0..1023
  const int cl1 = o >> 7, cl2 = cl1 + 8;
  for (int e = threadIdx.x; e < 5120; e += 256) {
    const int c = e / 320, s = e - c * 320;
    float v = 0.f;
    #pragma unroll
    for (int r = 0; r < 2; ++r) {
      const int ka = idx[((size_t)r * 2048 + o) * 16 + c];
      const int kb = idx[((size_t)r * 2048 + o + 1024) * 16 + c];
      v += cb[((((size_t)r * 16 + cl1) * 16 + c) * 64 + ka) * 320 + s];
      v += cb[((((size_t)r * 16 + cl2) * 16 + c) * 64 + kb) * 320 + s];
    }
    W[(size_t)o * 5120 + e] = __float2bfloat16(v);
  }
}

// ---------------- LayerNorm (no affine): x fp32 (4096,1024) -> xn bf16
__global__ __launch_bounds__(256) void ln_k(const float* __restrict__ x,
                                            __hip_bfloat16* __restrict__ xn) {
  const int row = blockIdx.x;
  const float4 v = ((const float4*)(x + (size_t)row * 1024))[threadIdx.x];
  float s = v.x + v.y + v.z + v.w;
  float s2 = v.x * v.x + v.y * v.y + v.z * v.z + v.w * v.w;
  #pragma unroll
  for (int off = 32; off > 0; off >>= 1) {
    s += __shfl_down(s, off, 64);
    s2 += __shfl_down(s2, off, 64);
  }
  __shared__ float red[8];
  if ((threadIdx.x & 63) == 0) { red[threadIdx.x >> 6] = s; red[4 + (threadIdx.x >> 6)] = s2; }
  __syncthreads();
  s = red[0] + red[1] + red[2] + red[3];
  s2 = red[4] + red[5] + red[6] + red[7];
  const float mu = s * (1.f / 1024.f);
  const float rstd = rsqrtf(s2 * (1.f / 1024.f) - mu * mu + 1e-5f);
  union { ushort4 u; unsigned short us[4]; } pk;
  const float vv[4] = {v.x, v.y, v.z, v.w};
  #pragma unroll
  for (int j = 0; j < 4; ++j) {
    __hip_bfloat16 bv = __float2bfloat16((vv[j] - mu) * rstd);
    pk.us[j] = *(unsigned short*)&bv;
  }
  *(ushort4*)(xn + (size_t)row * 1024 + threadIdx.x * 4) = pk.u;
}

// ---------------- GEMM1 (256x256, BK=32, 4-buffer depth-2 counted-vmcnt pipeline).
// h[m][o] = sum_c xn[m][c]*Win[o][c]. M=4096, N=7168, K=1024 (32 K-tiles).
// Stage tile t+3 during tile t; boundary waits vmcnt(8) (t+1,t+2 in flight) - never 0.
__global__ __launch_bounds__(512, 2) void gemm1_k(const __hip_bfloat16* __restrict__ A,
                                                  const __hip_bfloat16* __restrict__ B,
                                                  __hip_bfloat16* __restrict__ C,
                                                  __hip_bfloat16* __restrict__ vT) {
  __shared__ ushort sm[65536];  // 4 bufs x (A 8192 | B 8192) elems = 128 KiB
  const int tid = threadIdx.x;
  const int lane = tid & 63, wid = tid >> 6;
  const int g = lane >> 4, r16 = lane & 15;
  const int wr = wid >> 2, wc = wid & 3;

  int bid = blockIdx.x;                       // 448 blocks, 448%8==0
  bid = (bid & 7) * 56 + (bid >> 3);          // XCD-contiguous chunks
  const int mb = bid / 28, nb = bid % 28;
  const int m0 = mb * 256, n0 = nb * 256;

  // stage: 1024 chunks(16B)/operand/tile; per-wave 2 A + 2 B VMEM instructions.
  // LDS linear; source column-slot swizzled so read slot = g ^ ((row>>1)&3) (2-way free).
  auto stageA = [&](int kt, int buf) {
    #pragma unroll
    for (int i = 0; i < 2; ++i) {
      const int c = i * 512 + tid;
      const int row = c >> 2;
      const int sl = (c & 3) ^ ((row >> 1) & 3);
      async_ld16(&A[(size_t)(m0 + row) * 1024 + kt * 32 + sl * 8], &sm[buf * 16384 + c * 8]);
    }
  };
  auto stageB = [&](int kt, int buf) {
    #pragma unroll
    for (int i = 0; i < 2; ++i) {
      const int c = i * 512 + tid;
      const int row = c >> 2;
      const int sl = (c & 3) ^ ((row >> 1) & 3);
      async_ld16(&B[(size_t)(n0 + row) * 1024 + kt * 32 + sl * 8], &sm[buf * 16384 + 8192 + c * 8]);
    }
  };
  auto rdA = [&](int buf, int mm) -> short8 {
    const int row = wr * 128 + mm * 16 + r16;
    return *(const short8*)&sm[buf * 16384 + row * 32 + ((g ^ ((row >> 1) & 3)) * 8)];
  };
  auto rdB = [&](int buf, int nn) -> short8 {
    const int row = wc * 64 + nn * 16 + r16;
    return *(const short8*)&sm[buf * 16384 + 8192 + row * 32 + ((g ^ ((row >> 1) & 3)) * 8)];
  };

  f32x4 acc[8][4] = {};

  stageA(0, 0); stageB(0, 0);
  stageA(1, 1); stageB(1, 1);
  stageA(2, 2); stageB(2, 2);

  #pragma unroll 4
  for (int t = 0; t < 32; ++t) {
    const int buf = t & 3;
    if (t < 30)       asm volatile("s_waitcnt vmcnt(8)" ::: "memory");
    else if (t == 30) asm volatile("s_waitcnt vmcnt(4)" ::: "memory");
    else              asm volatile("s_waitcnt vmcnt(0)" ::: "memory");
    __builtin_amdgcn_s_barrier();
    __builtin_amdgcn_sched_barrier(0);
    if (t + 3 < 32) { stageA(t + 3, (t + 3) & 3); stageB(t + 3, (t + 3) & 3); }
    short8 a[8], b[4];
    #pragma unroll
    for (int mm = 0; mm < 8; ++mm) a[mm] = rdA(buf, mm);
    #pragma unroll
    for (int nn = 0; nn < 4; ++nn) b[nn] = rdB(buf, nn);
    __builtin_amdgcn_s_setprio(1);
    #pragma unroll
    for (int mm = 0; mm < 8; ++mm)
      #pragma unroll
      for (int nn = 0; nn < 4; ++nn)
        MFMA16(acc[mm][nn], a[mm], b[nn]);
    __builtin_amdgcn_s_setprio(0);
  }

  if (n0 < 6144) {
    #pragma unroll
    for (int mm = 0; mm < 8; ++mm)
      #pragma unroll
      for (int nn = 0; nn < 4; ++nn)
        #pragma unroll
        for (int r = 0; r < 4; ++r) {
          const int m = m0 + wr * 128 + mm * 16 + g * 4 + r;
          const int o = n0 + wc * 64 + nn * 16 + r16;
          C[(size_t)m * LDH + o] = __float2bfloat16(acc[mm][nn][r]);
        }
  } else {
    #pragma unroll
    for (int mm = 0; mm < 8; ++mm)
      #pragma unroll
      for (int nn = 0; nn < 4; ++nn)
        #pragma unroll
        for (int r = 0; r < 4; ++r) {
          const int m = m0 + wr * 128 + mm * 16 + g * 4 + r;
          const int o = n0 + wc * 64 + nn * 16 + r16;
          const int b_ = m >> 10;
          vT[((size_t)b_ * 1024 + (o - 6144)) * 1024 + (m & 1023)] = __float2bfloat16(acc[mm][nn][r]);
        }
  }
}

// ---------------- Flash attention: LDS-staged K/V, dbuf, counted vmcnt, swizzled source.
__global__ __launch_bounds__(256) void attn_k(const __hip_bfloat16* __restrict__ h,
                                              const __hip_bfloat16* __restrict__ vT,
                                              __hip_bfloat16* __restrict__ xa) {
  const int qt = blockIdx.x, head = blockIdx.y, b = blockIdx.z;
  const int tid = threadIdx.x;
  const int lane = tid & 63, w = tid >> 6;
  const int g = lane >> 4, r16 = lane & 15;

  __shared__ __align__(16) __hip_bfloat16 Ks[2][64 * 64];
  __shared__ __align__(16) __hip_bfloat16 Vs[2][64 * 64];
  __shared__ __align__(16) __hip_bfloat16 P[4][16][72];

  const __hip_bfloat16* Kg = h + (size_t)(b * 1024) * LDH + 5120 + head * 64;
  const __hip_bfloat16* Vg = vT + ((size_t)b * 1024 + head * 64) * 1024;

  const size_t qrow = (size_t)(b * 1024 + qt * 64 + w * 16 + r16);
  short8 aq0 = *(const short8*)&h[qrow * LDH + 4096 + head * 64 + g * 8];
  short8 aq1 = *(const short8*)&h[qrow * LDH + 4096 + head * 64 + 32 + g * 8];

  auto stage = [&](int buf, int t) {
    #pragma unroll
    for (int i = 0; i < 2; ++i) {
      const int c_lin = i * 256 + tid;
      const int row = c_lin >> 3;
      const int c_log = (c_lin & 7) ^ (row & 7);
      async_ld16(&Kg[(size_t)(t * 64 + row) * LDH + c_log * 8], &Ks[buf][c_lin * 8]);
    }
    #pragma unroll
    for (int i = 0; i < 2; ++i) {
      const int c_lin = i * 256 + tid;
      const int row = c_lin >> 3;
      const int c_log = (c_lin & 7) ^ (row & 7);
      async_ld16(&Vg[(size_t)row * 1024 + t * 64 + c_log * 8], &Vs[buf][c_lin * 8]);
    }
  };

  f32x4 o_acc[4] = {};
  float m_r[4], l_r[4];
  #pragma unroll
  for (int r = 0; r < 4; ++r) { m_r[r] = -1e30f; l_r[r] = 0.f; }

  stage(0, 0);
  for (int t = 0; t < 16; ++t) {
    const int buf = t & 1;
    if (t + 1 < 16) {
      stage(buf ^ 1, t + 1);
      asm volatile("s_waitcnt vmcnt(4)" ::: "memory");
    } else {
      asm volatile("s_waitcnt vmcnt(0)" ::: "memory");
    }
    __builtin_amdgcn_s_barrier();
    __builtin_amdgcn_sched_barrier(0);

    f32x4 s_acc[4] = {};
    #pragma unroll
    for (int nn = 0; nn < 4; ++nn) {
      const int row = nn * 16 + r16;
      short8 bk0 = *(const short8*)&Ks[buf][row * 64 + ((g ^ (row & 7)) * 8)];
      short8 bk1 = *(const short8*)&Ks[buf][row * 64 + (((g + 4) ^ (row & 7)) * 8)];
      s_acc[nn] = __builtin_amdgcn_mfma_f32_16x16x32_bf16(aq0, bk0, s_acc[nn], 0, 0, 0);
      s_acc[nn] = __builtin_amdgcn_mfma_f32_16x16x32_bf16(aq1, bk1, s_acc[nn], 0, 0, 0);
    }
    #pragma unroll
    for (int nn = 0; nn < 4; ++nn) s_acc[nn] *= 0.125f;

    #pragma unroll
    for (int r = 0; r < 4; ++r) {
      float mx = fmaxf(fmaxf(s_acc[0][r], s_acc[1][r]), fmaxf(s_acc[2][r], s_acc[3][r]));
      #pragma unroll
      for (int off = 1; off < 16; off <<= 1) mx = fmaxf(mx, __shfl_xor(mx, off, 64));
      const float mn = fmaxf(m_r[r], mx);
      const float al = __expf(m_r[r] - mn);
      m_r[r] = mn;
      float ps = 0.f;
      #pragma unroll
      for (int nn = 0; nn < 4; ++nn) {
        const float p = __expf(s_acc[nn][r] - mn);
        s_acc[nn][r] = p;
        ps += p;
      }
      #pragma unroll
      for (int off = 1; off < 16; off <<= 1) ps += __shfl_xor(ps, off, 64);
      l_r[r] = l_r[r] * al + ps;
      o_acc[0][r] *= al; o_acc[1][r] *= al; o_acc[2][r] *= al; o_acc[3][r] *= al;
    }

    #pragma unroll
    for (int nn = 0; nn < 4; ++nn)
      #pragma unroll
      for (int r = 0; r < 4; ++r)
        P[w][g * 4 + r][nn * 16 + r16] = __float2bfloat16(s_acc[nn][r]);
    short8 ap0 = *(const short8*)&P[w][r16][g * 8];
    short8 ap1 = *(const short8*)&P[w][r16][32 + g * 8];

    #pragma unroll
    for (int nn = 0; nn < 4; ++nn) {
      const int row = nn * 16 + r16;
      short8 bv0 = *(const short8*)&Vs[buf][row * 64 + ((g ^ (row & 7)) * 8)];
      short8 bv1 = *(const short8*)&Vs[buf][row * 64 + (((g + 4) ^ (row & 7)) * 8)];
      o_acc[nn] = __builtin_amdgcn_mfma_f32_16x16x32_bf16(ap0, bv0, o_acc[nn], 0, 0, 0);
      o_acc[nn] = __builtin_amdgcn_mfma_f32_16x16x32_bf16(ap1, bv1, o_acc[nn], 0, 0, 0);
    }
    __builtin_amdgcn_s_barrier();
    __builtin_amdgcn_sched_barrier(0);
  }

  #pragma unroll
  for (int r = 0; r < 4; ++r) {
    const float inv = 1.0f / l_r[r];
    const size_t mrow = (size_t)(b * 1024 + qt * 64 + w * 16 + g * 4 + r);
    #pragma unroll
    for (int nn = 0; nn < 4; ++nn)
      xa[mrow * 1024 + head * 64 + nn * 16 + r16] = __float2bfloat16(o_acc[nn][r] * inv);
  }
}

// ---------------- GEMM2 (256x256, BK=32, 4-buffer depth-2 pipeline, split-K 4).
// M=4096,N=1024,K=5120; z covers global K-tiles [z*40, z*40+40) (slice 1280).
__global__ __launch_bounds__(512, 2) void gemm2_k(const __hip_bfloat16* __restrict__ h,
                                                  const __hip_bfloat16* __restrict__ xa,
                                                  const __hip_bfloat16* __restrict__ W,
                                                  __hip_bfloat16* __restrict__ p0,
                                                  __hip_bfloat16* __restrict__ p1,
                                                  __hip_bfloat16* __restrict__ p2,
                                                  float* __restrict__ out) {
  __shared__ ushort sm[65536];
  const int tid = threadIdx.x;
  const int lane = tid & 63, wid = tid >> 6;
  const int g = lane >> 4, r16 = lane & 15;
  const int wr = wid >> 2, wc = wid & 3;

  int bid = blockIdx.x;                       // 64 tiles
  bid = (bid & 7) * 8 + (bid >> 3);           // XCD-contiguous chunks
  const int mb = bid >> 2, nb = bid & 3;
  const int m0 = mb * 256, n0 = nb * 256;
  const int z = blockIdx.y;
  const int kt0 = z * 40;

  auto stageA = [&](int ktl, int buf) {       // ktl = local tile 0..39
    const int ktg = kt0 + ktl;
    const __hip_bfloat16* Ab; size_t lda; int kc;
    if (ktg < 128) { Ab = h;  lda = LDH;  kc = ktg * 32; }
    else           { Ab = xa; lda = 1024; kc = ktg * 32 - 4096; }
    #pragma unroll
    for (int i = 0; i < 2; ++i) {
      const int c = i * 512 + tid;
      const int row = c >> 2;
      const int sl = (c & 3) ^ ((row >> 1) & 3);
      async_ld16(&Ab[(size_t)(m0 + row) * lda + kc + sl * 8], &sm[buf * 16384 + c * 8]);
    }
  };
  auto stageB = [&](int ktl, int buf) {
    const int ktg = kt0 + ktl;
    #pragma unroll
    for (int i = 0; i < 2; ++i) {
      const int c = i * 512 + tid;
      const int row = c >> 2;
      const int sl = (c & 3) ^ ((row >> 1) & 3);
      async_ld16(&W[(size_t)(n0 + row) * 5120 + ktg * 32 + sl * 8], &sm[buf * 16384 + 8192 + c * 8]);
    }
  };
  auto rdA = [&](int buf, int mm) -> short8 {
    const int row = wr * 128 + mm * 16 + r16;
    return *(const short8*)&sm[buf * 16384 + row * 32 + ((g ^ ((row >> 1) & 3)) * 8)];
  };
  auto rdB = [&](int buf, int nn) -> short8 {
    const int row = wc * 64 + nn * 16 + r16;
    return *(const short8*)&sm[buf * 16384 + 8192 + row * 32 + ((g ^ ((row >> 1) & 3)) * 8)];
  };

  f32x4 acc[8][4] = {};

  stageA(0, 0); stageB(0, 0);
  stageA(1, 1); stageB(1, 1);
  stageA(2, 2); stageB(2, 2);

  #pragma unroll 4
  for (int t = 0; t < 40; ++t) {
    const int buf = t & 3;
    if (t < 38)       asm volatile("s_waitcnt vmcnt(8)" ::: "memory");
    else if (t == 38) asm volatile("s_waitcnt vmcnt(4)" ::: "memory");
    else              asm volatile("s_waitcnt vmcnt(0)" ::: "memory");
    __builtin_amdgcn_s_barrier();
    __builtin_amdgcn_sched_barrier(0);
    if (t + 3 < 40) { stageA(t + 3, (t + 3) & 3); stageB(t + 3, (t + 3) & 3); }
    short8 a[8], b[4];
    #pragma unroll
    for (int mm = 0; mm < 8; ++mm) a[mm] = rdA(buf, mm);
    #pragma unroll
    for (int nn = 0; nn < 4; ++nn) b[nn] = rdB(buf, nn);
    __builtin_amdgcn_s_setprio(1);
    #pragma unroll
    for (int mm = 0; mm < 8; ++mm)
      #pragma unroll
      for (int nn = 0; nn < 4; ++nn)
        MFMA16(acc[mm][nn], a[mm], b[nn]);
    __builtin_amdgcn_s_setprio(0);
  }

  __hip_bfloat16* pz = (z == 0) ? p0 : (z == 1) ? p1 : p2;
  #pragma unroll
  for (int mm = 0; mm < 8; ++mm)
    #pragma unroll
    for (int nn = 0; nn < 4; ++nn)
      #pragma unroll
      for (int r = 0; r < 4; ++r) {
        const int m = m0 + wr * 128 + mm * 16 + g * 4 + r;
        const int n = n0 + wc * 64 + nn * 16 + r16;
        if (z == 3) out[(size_t)m * 1024 + n] = acc[mm][nn][r];
        else        pz[(size_t)m * 1024 + n] = __float2bfloat16(acc[mm][nn][r]);
      }
}

// ---------------- reduce: out = out + p0 + p1 + p2 + res
__global__ __launch_bounds__(256) void reduce_k(const __hip_bfloat16* __restrict__ p0,
                                                const __hip_bfloat16* __restrict__ p1,
                                                const __hip_bfloat16* __restrict__ p2,
                                                const float* __restrict__ res,
                                                float* __restrict__ out) {
  const size_t i4 = (size_t)blockIdx.x * 256 + threadIdx.x;
  float4 o = ((const float4*)out)[i4];
  const float4 rr = ((const float4*)res)[i4];
  const ushort4 a0 = ((const ushort4*)p0)[i4];
  const ushort4 a1 = ((const ushort4*)p1)[i4];
  const ushort4 a2 = ((const ushort4*)p2)[i4];
  o.x += rr.x + bf2f(a0.x) + bf2f(a1.x) + bf2f(a2.x);
  o.y += rr.y + bf2f(a0.y) + bf2f(a1.y) + bf2f(a2.y);
  o.z += rr.z + bf2f(a0.z) + bf2f(a1.z) + bf2f(a2.z);
  o.w += rr.w + bf2f(a0.w) + bf2f(a1.w) + bf2f(a2.w);
  ((float4*)out)[i4] = o;
}

extern "C" void kernel_launch(void* const* d_in, const int* in_sizes, int n_in,
                              void* d_out, int out_size, void* d_ws, size_t ws_size,
                              hipStream_t stream) {
  (void)in_sizes; (void)n_in; (void)out_size; (void)ws_size;
  const float* x      = (const float*)d_in[0];
  const float* in_cb  = (const float*)d_in[1];
  const int*   in_idx = (const int*)d_in[2];
  const float* out_cb = (const float*)d_in[3];
  const int*   out_idx= (const int*)d_in[4];
  float* out = (float*)d_out;
  char* ws = (char*)d_ws;

  __hip_bfloat16* Win  = (__hip_bfloat16*)(ws);                 // 14,680,064
  __hip_bfloat16* Weff = (__hip_bfloat16*)(ws + 14680064);      // 10,485,760
  __hip_bfloat16* xn   = (__hip_bfloat16*)(ws + 25165824);      //  8,388,608
  __hip_bfloat16* h    = (__hip_bfloat16*)(ws + 33554432);      // 58,720,256
  __hip_bfloat16* vT   = (__hip_bfloat16*)(ws + 92274688);      //  8,388,608
  __hip_bfloat16* xa   = (__hip_bfloat16*)(ws + 100663296);     //  8,388,608

  __hip_bfloat16* pk0 = Win;   // dead after gemm1
  __hip_bfloat16* pk1 = xn;    // dead after gemm1
  __hip_bfloat16* pk2 = vT;    // dead after attn

  decode_win_k<<<dim3(7168), dim3(256), 0, stream>>>(in_cb, in_idx, Win);
  decode_weff_k<<<dim3(1024), dim3(256), 0, stream>>>(out_cb, out_idx, Weff);
  ln_k<<<dim3(4096), dim3(256), 0, stream>>>(x, xn);
  gemm1_k<<<dim3(448), dim3(512), 0, stream>>>(xn, Win, h, vT);
  attn_k<<<dim3(16, 16, 4), dim3(256), 0, stream>>>(h, vT, xa);
  gemm2_k<<<dim3(64, 4), dim3(512), 0, stream>>>(h, xa, Weff, pk0, pk1, pk2, out);
  reduce_k<<<dim3(4096), dim3(256), 0, stream>>>(pk0, pk1, pk2, x, out);
}

// Round 8
// 219.203 us; speedup vs baseline: 1.4341x; 1.4341x over previous
//
#include <hip/hip_runtime.h>
#include <hip/hip_bf16.h>

typedef float f32x4 __attribute__((ext_vector_type(4)));
typedef short short8 __attribute__((ext_vector_type(8)));

#define LDH 7168
#define MFMA16(d, x, y) d = __builtin_amdgcn_mfma_f32_16x16x32_bf16(x, y, d, 0, 0, 0)

__device__ __forceinline__ void async_ld16(const void* g, void* l) {
  __builtin_amdgcn_global_load_lds(
      (const __attribute__((address_space(1))) unsigned int*)g,
      (__attribute__((address_space(3))) unsigned int*)l, 16, 0, 0);
}

__device__ __forceinline__ float bf2f(unsigned short u) {
  union { unsigned int i; float f; } c; c.i = ((unsigned int)u) << 16; return c.f;
}

__device__ __forceinline__ ushort4 pack_bf16x4(float4 v) {
  ushort4 u;
  __hip_bfloat16 b;
  b = __float2bfloat16(v.x); u.x = *(unsigned short*)&b;
  b = __float2bfloat16(v.y); u.y = *(unsigned short*)&b;
  b = __float2bfloat16(v.z); u.z = *(unsigned short*)&b;
  b = __float2bfloat16(v.w); u.w = *(unsigned short*)&b;
  return u;
}

// ---------------- decode Win: (7168,1024) bf16 — vectorized (float4 in, ushort4 out)
__global__ __launch_bounds__(256) void decode_win_k(const float* __restrict__ cb,
                                                    const int* __restrict__ idx,
                                                    __hip_bfloat16* __restrict__ Win) {
  const int o = blockIdx.x;
  const int cluster = o >> 6;
  const int c = threadIdx.x >> 4;            // 0..15
  const int s4 = (threadIdx.x & 15) * 4;     // 0..60
  const int k0 = idx[o * 16 + c];
  const int k1 = idx[(7168 + o) * 16 + c];
  const float4 v0 = *(const float4*)&cb[((((size_t)cluster) * 16 + c) * 64 + k0) * 64 + s4];
  const float4 v1 = *(const float4*)&cb[((((size_t)(112 + cluster)) * 16 + c) * 64 + k1) * 64 + s4];
  float4 v; v.x = v0.x + v1.x; v.y = v0.y + v1.y; v.z = v0.z + v1.z; v.w = v0.w + v1.w;
  *(ushort4*)&Win[(size_t)o * 1024 + c * 64 + s4] = pack_bf16x4(v);
}

// ---------------- decode Weff: (1024,5120) bf16 = Wout[o] + Wout[o+1024], summed over R — vectorized
__global__ __launch_bounds__(256) void decode_weff_k(const float* __restrict__ cb,
                                                     const int* __restrict__ idx,
                                                     __hip_bfloat16* __restrict__ W) {
  const int o = blockIdx.x;          // 0..1023
  const int cl1 = o >> 7, cl2 = cl1 + 8;
  for (int e4 = threadIdx.x * 4; e4 < 5120; e4 += 1024) {
    const int c = e4 / 320, s = e4 - c * 320;
    float4 acc = {0.f, 0.f, 0.f, 0.f};
    #pragma unroll
    for (int r = 0; r < 2; ++r) {
      const int ka = idx[((size_t)r * 2048 + o) * 16 + c];
      const int kb = idx[((size_t)r * 2048 + o + 1024) * 16 + c];
      const float4 va = *(const float4*)&cb[((((size_t)r * 16 + cl1) * 16 + c) * 64 + ka) * 320 + s];
      const float4 vb = *(const float4*)&cb[((((size_t)r * 16 + cl2) * 16 + c) * 64 + kb) * 320 + s];
      acc.x += va.x + vb.x; acc.y += va.y + vb.y; acc.z += va.z + vb.z; acc.w += va.w + vb.w;
    }
    *(ushort4*)&W[(size_t)o * 5120 + e4] = pack_bf16x4(acc);
  }
}

// ---------------- LayerNorm (no affine): x fp32 (4096,1024) -> xn bf16
__global__ __launch_bounds__(256) void ln_k(const float* __restrict__ x,
                                            __hip_bfloat16* __restrict__ xn) {
  const int row = blockIdx.x;
  const float4 v = ((const float4*)(x + (size_t)row * 1024))[threadIdx.x];
  float s = v.x + v.y + v.z + v.w;
  float s2 = v.x * v.x + v.y * v.y + v.z * v.z + v.w * v.w;
  #pragma unroll
  for (int off = 32; off > 0; off >>= 1) {
    s += __shfl_down(s, off, 64);
    s2 += __shfl_down(s2, off, 64);
  }
  __shared__ float red[8];
  if ((threadIdx.x & 63) == 0) { red[threadIdx.x >> 6] = s; red[4 + (threadIdx.x >> 6)] = s2; }
  __syncthreads();
  s = red[0] + red[1] + red[2] + red[3];
  s2 = red[4] + red[5] + red[6] + red[7];
  const float mu = s * (1.f / 1024.f);
  const float rstd = rsqrtf(s2 * (1.f / 1024.f) - mu * mu + 1e-5f);
  float4 nv;
  nv.x = (v.x - mu) * rstd; nv.y = (v.y - mu) * rstd;
  nv.z = (v.z - mu) * rstd; nv.w = (v.w - mu) * rstd;
  *(ushort4*)(xn + (size_t)row * 1024 + threadIdx.x * 4) = pack_bf16x4(nv);
}

// ---------------- GEMM1 (256x256 8-phase, round-4 proven schedule + 2D-XCD map).
// h[m][o] = sum_c xn[m][c]*Win[o][c]. M=4096, N=7168, K=1024.
__global__ __launch_bounds__(512, 2) void gemm1_k(const __hip_bfloat16* __restrict__ A,
                                                  const __hip_bfloat16* __restrict__ B,
                                                  __hip_bfloat16* __restrict__ C,
                                                  __hip_bfloat16* __restrict__ vT) {
  __shared__ ushort sm[65536];  // [buf][A 16384 | B 16384] elems = 128 KiB
  const int tid = threadIdx.x;
  const int lane = tid & 63, wid = tid >> 6;
  const int g = lane >> 4, r16 = lane & 15;
  const int wr = wid >> 2, wc = wid & 3;

  // 2D XCD map: XCD x covers a 4(M) x 14(N) tile rectangle -> per-XCD footprint
  // 2MB A + 7.3MB B (was: all 14.7MB of B per XCD).
  const int x = blockIdx.x & 7, local = blockIdx.x >> 3;   // 448 blocks
  const int mb = (x >> 1) * 4 + local / 14;
  const int nb = (x & 1) * 14 + local % 14;
  const int m0 = mb * 256, n0 = nb * 256;

  auto stageA = [&](int kt, int base) {
    #pragma unroll
    for (int i = 0; i < 4; ++i) {
      const int c = i * 512 + tid;
      const int lc = c ^ (((c >> 5) & 1) << 1);
      const int row = lc >> 3, col = (lc & 7) * 8;
      async_ld16(&A[(size_t)(m0 + row) * 1024 + kt * 64 + col], &sm[base + c * 8]);
    }
  };
  auto stageB = [&](int kt, int base) {
    #pragma unroll
    for (int i = 0; i < 4; ++i) {
      const int c = i * 512 + tid;
      const int lc = c ^ (((c >> 5) & 1) << 1);
      const int row = lc >> 3, col = (lc & 7) * 8;
      async_ld16(&B[(size_t)(n0 + row) * 1024 + kt * 64 + col], &sm[base + 16384 + c * 8]);
    }
  };
  auto rdA = [&](int base, int mm, int kk) -> short8 {
    const int row = wr * 128 + mm * 16 + r16;
    int e = row * 64 + kk * 32 + g * 8;
    e ^= ((row >> 2) & 1) << 4;
    return *(const short8*)&sm[base + e];
  };
  auto rdB = [&](int base, int nn, int kk) -> short8 {
    const int row = wc * 64 + nn * 16 + r16;
    int e = row * 64 + kk * 32 + g * 8;
    e ^= ((row >> 2) & 1) << 4;
    return *(const short8*)&sm[base + 16384 + e];
  };

  f32x4 acc[8][4] = {};

  stageA(0, 0); stageB(0, 0);
  asm volatile("s_waitcnt vmcnt(0)" ::: "memory");
  __builtin_amdgcn_s_barrier();
  __builtin_amdgcn_sched_barrier(0);

  auto tile_body = [&](int kt, int base, int nbase) {
    short8 a0[4][2], a1[4][2], b0[2][2], b1[2][2];
    // ph1: A-quad0 + B-quad0 reads; issue next A; MFMA (qm0,qn0)
    #pragma unroll
    for (int mm = 0; mm < 4; ++mm) { a0[mm][0] = rdA(base, mm, 0); a0[mm][1] = rdA(base, mm, 1); }
    #pragma unroll
    for (int nn = 0; nn < 2; ++nn) { b0[nn][0] = rdB(base, nn, 0); b0[nn][1] = rdB(base, nn, 1); }
    if (kt + 1 < 16) stageA(kt + 1, nbase);
    __builtin_amdgcn_s_setprio(1);
    #pragma unroll
    for (int mm = 0; mm < 4; ++mm)
      #pragma unroll
      for (int nn = 0; nn < 2; ++nn) {
        MFMA16(acc[mm][nn], a0[mm][0], b0[nn][0]);
        MFMA16(acc[mm][nn], a0[mm][1], b0[nn][1]);
      }
    __builtin_amdgcn_s_setprio(0);
    __builtin_amdgcn_s_barrier();
    // ph2: B-quad1 reads; issue next B; MFMA (qm0,qn1)
    #pragma unroll
    for (int nn = 0; nn < 2; ++nn) { b1[nn][0] = rdB(base, 2 + nn, 0); b1[nn][1] = rdB(base, 2 + nn, 1); }
    if (kt + 1 < 16) stageB(kt + 1, nbase);
    __builtin_amdgcn_s_setprio(1);
    #pragma unroll
    for (int mm = 0; mm < 4; ++mm)
      #pragma unroll
      for (int nn = 0; nn < 2; ++nn) {
        MFMA16(acc[mm][2 + nn], a0[mm][0], b1[nn][0]);
        MFMA16(acc[mm][2 + nn], a0[mm][1], b1[nn][1]);
      }
    __builtin_amdgcn_s_setprio(0);
    __builtin_amdgcn_s_barrier();
    // ph3: A-quad1 reads; MFMA (qm1,qn1)
    #pragma unroll
    for (int mm = 0; mm < 4; ++mm) { a1[mm][0] = rdA(base, 4 + mm, 0); a1[mm][1] = rdA(base, 4 + mm, 1); }
    __builtin_amdgcn_s_setprio(1);
    #pragma unroll
    for (int mm = 0; mm < 4; ++mm)
      #pragma unroll
      for (int nn = 0; nn < 2; ++nn) {
        MFMA16(acc[4 + mm][2 + nn], a1[mm][0], b1[nn][0]);
        MFMA16(acc[4 + mm][2 + nn], a1[mm][1], b1[nn][1]);
      }
    __builtin_amdgcn_s_setprio(0);
    __builtin_amdgcn_s_barrier();
    // ph4: MFMA (qm1,qn0); drain; boundary
    __builtin_amdgcn_s_setprio(1);
    #pragma unroll
    for (int mm = 0; mm < 4; ++mm)
      #pragma unroll
      for (int nn = 0; nn < 2; ++nn) {
        MFMA16(acc[4 + mm][nn], a1[mm][0], b0[nn][0]);
        MFMA16(acc[4 + mm][nn], a1[mm][1], b0[nn][1]);
      }
    __builtin_amdgcn_s_setprio(0);
    asm volatile("s_waitcnt vmcnt(0) lgkmcnt(0)" ::: "memory");
    __builtin_amdgcn_s_barrier();
    __builtin_amdgcn_sched_barrier(0);
  };

  for (int kt = 0; kt < 16; kt += 2) {
    tile_body(kt, 0, 32768);
    tile_body(kt + 1, 32768, 0);
  }

  if (n0 < 6144) {
    #pragma unroll
    for (int mm = 0; mm < 8; ++mm)
      #pragma unroll
      for (int nn = 0; nn < 4; ++nn)
        #pragma unroll
        for (int r = 0; r < 4; ++r) {
          const int m = m0 + wr * 128 + mm * 16 + g * 4 + r;
          const int o = n0 + wc * 64 + nn * 16 + r16;
          C[(size_t)m * LDH + o] = __float2bfloat16(acc[mm][nn][r]);
        }
  } else {
    #pragma unroll
    for (int mm = 0; mm < 8; ++mm)
      #pragma unroll
      for (int nn = 0; nn < 4; ++nn)
        #pragma unroll
        for (int r = 0; r < 4; ++r) {
          const int m = m0 + wr * 128 + mm * 16 + g * 4 + r;
          const int o = n0 + wc * 64 + nn * 16 + r16;
          const int b_ = m >> 10;
          vT[((size_t)b_ * 1024 + (o - 6144)) * 1024 + (m & 1023)] = __float2bfloat16(acc[mm][nn][r]);
        }
  }
}

// ---------------- Flash attention: LDS-staged K/V, dbuf, counted vmcnt, swizzled source.
__global__ __launch_bounds__(256) void attn_k(const __hip_bfloat16* __restrict__ h,
                                              const __hip_bfloat16* __restrict__ vT,
                                              __hip_bfloat16* __restrict__ xa) {
  const int qt = blockIdx.x, head = blockIdx.y, b = blockIdx.z;
  const int tid = threadIdx.x;
  const int lane = tid & 63, w = tid >> 6;
  const int g = lane >> 4, r16 = lane & 15;

  __shared__ __align__(16) __hip_bfloat16 Ks[2][64 * 64];
  __shared__ __align__(16) __hip_bfloat16 Vs[2][64 * 64];
  __shared__ __align__(16) __hip_bfloat16 P[4][16][72];

  const __hip_bfloat16* Kg = h + (size_t)(b * 1024) * LDH + 5120 + head * 64;
  const __hip_bfloat16* Vg = vT + ((size_t)b * 1024 + head * 64) * 1024;

  const size_t qrow = (size_t)(b * 1024 + qt * 64 + w * 16 + r16);
  short8 aq0 = *(const short8*)&h[qrow * LDH + 4096 + head * 64 + g * 8];
  short8 aq1 = *(const short8*)&h[qrow * LDH + 4096 + head * 64 + 32 + g * 8];

  auto stage = [&](int buf, int t) {
    #pragma unroll
    for (int i = 0; i < 2; ++i) {
      const int c_lin = i * 256 + tid;
      const int row = c_lin >> 3;
      const int c_log = (c_lin & 7) ^ (row & 7);
      async_ld16(&Kg[(size_t)(t * 64 + row) * LDH + c_log * 8], &Ks[buf][c_lin * 8]);
    }
    #pragma unroll
    for (int i = 0; i < 2; ++i) {
      const int c_lin = i * 256 + tid;
      const int row = c_lin >> 3;
      const int c_log = (c_lin & 7) ^ (row & 7);
      async_ld16(&Vg[(size_t)row * 1024 + t * 64 + c_log * 8], &Vs[buf][c_lin * 8]);
    }
  };

  f32x4 o_acc[4] = {};
  float m_r[4], l_r[4];
  #pragma unroll
  for (int r = 0; r < 4; ++r) { m_r[r] = -1e30f; l_r[r] = 0.f; }

  stage(0, 0);
  for (int t = 0; t < 16; ++t) {
    const int buf = t & 1;
    if (t + 1 < 16) {
      stage(buf ^ 1, t + 1);
      asm volatile("s_waitcnt vmcnt(4)" ::: "memory");
    } else {
      asm volatile("s_waitcnt vmcnt(0)" ::: "memory");
    }
    __builtin_amdgcn_s_barrier();
    __builtin_amdgcn_sched_barrier(0);

    f32x4 s_acc[4] = {};
    #pragma unroll
    for (int nn = 0; nn < 4; ++nn) {
      const int row = nn * 16 + r16;
      short8 bk0 = *(const short8*)&Ks[buf][row * 64 + ((g ^ (row & 7)) * 8)];
      short8 bk1 = *(const short8*)&Ks[buf][row * 64 + (((g + 4) ^ (row & 7)) * 8)];
      s_acc[nn] = __builtin_amdgcn_mfma_f32_16x16x32_bf16(aq0, bk0, s_acc[nn], 0, 0, 0);
      s_acc[nn] = __builtin_amdgcn_mfma_f32_16x16x32_bf16(aq1, bk1, s_acc[nn], 0, 0, 0);
    }
    #pragma unroll
    for (int nn = 0; nn < 4; ++nn) s_acc[nn] *= 0.125f;

    #pragma unroll
    for (int r = 0; r < 4; ++r) {
      float mx = fmaxf(fmaxf(s_acc[0][r], s_acc[1][r]), fmaxf(s_acc[2][r], s_acc[3][r]));
      #pragma unroll
      for (int off = 1; off < 16; off <<= 1) mx = fmaxf(mx, __shfl_xor(mx, off, 64));
      const float mn = fmaxf(m_r[r], mx);
      const float al = __expf(m_r[r] - mn);
      m_r[r] = mn;
      float ps = 0.f;
      #pragma unroll
      for (int nn = 0; nn < 4; ++nn) {
        const float p = __expf(s_acc[nn][r] - mn);
        s_acc[nn][r] = p;
        ps += p;
      }
      #pragma unroll
      for (int off = 1; off < 16; off <<= 1) ps += __shfl_xor(ps, off, 64);
      l_r[r] = l_r[r] * al + ps;
      o_acc[0][r] *= al; o_acc[1][r] *= al; o_acc[2][r] *= al; o_acc[3][r] *= al;
    }

    #pragma unroll
    for (int nn = 0; nn < 4; ++nn)
      #pragma unroll
      for (int r = 0; r < 4; ++r)
        P[w][g * 4 + r][nn * 16 + r16] = __float2bfloat16(s_acc[nn][r]);
    short8 ap0 = *(const short8*)&P[w][r16][g * 8];
    short8 ap1 = *(const short8*)&P[w][r16][32 + g * 8];

    #pragma unroll
    for (int nn = 0; nn < 4; ++nn) {
      const int row = nn * 16 + r16;
      short8 bv0 = *(const short8*)&Vs[buf][row * 64 + ((g ^ (row & 7)) * 8)];
      short8 bv1 = *(const short8*)&Vs[buf][row * 64 + (((g + 4) ^ (row & 7)) * 8)];
      o_acc[nn] = __builtin_amdgcn_mfma_f32_16x16x32_bf16(ap0, bv0, o_acc[nn], 0, 0, 0);
      o_acc[nn] = __builtin_amdgcn_mfma_f32_16x16x32_bf16(ap1, bv1, o_acc[nn], 0, 0, 0);
    }
    __builtin_amdgcn_s_barrier();
    __builtin_amdgcn_sched_barrier(0);
  }

  #pragma unroll
  for (int r = 0; r < 4; ++r) {
    const float inv = 1.0f / l_r[r];
    const size_t mrow = (size_t)(b * 1024 + qt * 64 + w * 16 + g * 4 + r);
    #pragma unroll
    for (int nn = 0; nn < 4; ++nn)
      xa[mrow * 1024 + head * 64 + nn * 16 + r16] = __float2bfloat16(o_acc[nn][r] * inv);
  }
}

// ---------------- GEMM2 (256x256 8-phase, split-K 4, round-4 proven schedule).
// M=4096, N=1024, K=5120; z covers K-tiles [z*20, z*20+20) (K-slice 1280).
__global__ __launch_bounds__(512, 2) void gemm2_k(const __hip_bfloat16* __restrict__ h,
                                                  const __hip_bfloat16* __restrict__ xa,
                                                  const __hip_bfloat16* __restrict__ W,
                                                  __hip_bfloat16* __restrict__ p0,
                                                  __hip_bfloat16* __restrict__ p1,
                                                  __hip_bfloat16* __restrict__ p2,
                                                  float* __restrict__ out) {
  __shared__ ushort sm[65536];
  const int tid = threadIdx.x;
  const int lane = tid & 63, wid = tid >> 6;
  const int g = lane >> 4, r16 = lane & 15;
  const int wr = wid >> 2, wc = wid & 3;

  int bid = blockIdx.x;                       // 64 tiles, 64%8==0
  bid = (bid & 7) * 8 + (bid >> 3);           // XCD-contiguous chunks
  const int mb = bid >> 2, nb = bid & 3;
  const int m0 = mb * 256, n0 = nb * 256;
  const int z = blockIdx.y;
  const int kt0 = z * 20, ktEnd = kt0 + 20;

  auto stageA = [&](int kt, int base) {
    const __hip_bfloat16* Ab; size_t lda; int kc;
    if (kt < 64) { Ab = h;  lda = LDH;  kc = kt * 64; }
    else         { Ab = xa; lda = 1024; kc = kt * 64 - 4096; }
    #pragma unroll
    for (int i = 0; i < 4; ++i) {
      const int c = i * 512 + tid;
      const int lc = c ^ (((c >> 5) & 1) << 1);
      const int row = lc >> 3, col = (lc & 7) * 8;
      async_ld16(&Ab[(size_t)(m0 + row) * lda + kc + col], &sm[base + c * 8]);
    }
  };
  auto stageB = [&](int kt, int base) {
    #pragma unroll
    for (int i = 0; i < 4; ++i) {
      const int c = i * 512 + tid;
      const int lc = c ^ (((c >> 5) & 1) << 1);
      const int row = lc >> 3, col = (lc & 7) * 8;
      async_ld16(&W[(size_t)(n0 + row) * 5120 + kt * 64 + col], &sm[base + 16384 + c * 8]);
    }
  };
  auto rdA = [&](int base, int mm, int kk) -> short8 {
    const int row = wr * 128 + mm * 16 + r16;
    int e = row * 64 + kk * 32 + g * 8;
    e ^= ((row >> 2) & 1) << 4;
    return *(const short8*)&sm[base + e];
  };
  auto rdB = [&](int base, int nn, int kk) -> short8 {
    const int row = wc * 64 + nn * 16 + r16;
    int e = row * 64 + kk * 32 + g * 8;
    e ^= ((row >> 2) & 1) << 4;
    return *(const short8*)&sm[base + 16384 + e];
  };

  f32x4 acc[8][4] = {};

  stageA(kt0, 0); stageB(kt0, 0);
  asm volatile("s_waitcnt vmcnt(0)" ::: "memory");
  __builtin_amdgcn_s_barrier();
  __builtin_amdgcn_sched_barrier(0);

  auto tile_body = [&](int kt, int base, int nbase) {
    short8 a0[4][2], a1[4][2], b0[2][2], b1[2][2];
    #pragma unroll
    for (int mm = 0; mm < 4; ++mm) { a0[mm][0] = rdA(base, mm, 0); a0[mm][1] = rdA(base, mm, 1); }
    #pragma unroll
    for (int nn = 0; nn < 2; ++nn) { b0[nn][0] = rdB(base, nn, 0); b0[nn][1] = rdB(base, nn, 1); }
    if (kt + 1 < ktEnd) stageA(kt + 1, nbase);
    __builtin_amdgcn_s_setprio(1);
    #pragma unroll
    for (int mm = 0; mm < 4; ++mm)
      #pragma unroll
      for (int nn = 0; nn < 2; ++nn) {
        MFMA16(acc[mm][nn], a0[mm][0], b0[nn][0]);
        MFMA16(acc[mm][nn], a0[mm][1], b0[nn][1]);
      }
    __builtin_amdgcn_s_setprio(0);
    __builtin_amdgcn_s_barrier();
    #pragma unroll
    for (int nn = 0; nn < 2; ++nn) { b1[nn][0] = rdB(base, 2 + nn, 0); b1[nn][1] = rdB(base, 2 + nn, 1); }
    if (kt + 1 < ktEnd) stageB(kt + 1, nbase);
    __builtin_amdgcn_s_setprio(1);
    #pragma unroll
    for (int mm = 0; mm < 4; ++mm)
      #pragma unroll
      for (int nn = 0; nn < 2; ++nn) {
        MFMA16(acc[mm][2 + nn], a0[mm][0], b1[nn][0]);
        MFMA16(acc[mm][2 + nn], a0[mm][1], b1[nn][1]);
      }
    __builtin_amdgcn_s_setprio(0);
    __builtin_amdgcn_s_barrier();
    #pragma unroll
    for (int mm = 0; mm < 4; ++mm) { a1[mm][0] = rdA(base, 4 + mm, 0); a1[mm][1] = rdA(base, 4 + mm, 1); }
    __builtin_amdgcn_s_setprio(1);
    #pragma unroll
    for (int mm = 0; mm < 4; ++mm)
      #pragma unroll
      for (int nn = 0; nn < 2; ++nn) {
        MFMA16(acc[4 + mm][2 + nn], a1[mm][0], b1[nn][0]);
        MFMA16(acc[4 + mm][2 + nn], a1[mm][1], b1[nn][1]);
      }
    __builtin_amdgcn_s_setprio(0);
    __builtin_amdgcn_s_barrier();
    __builtin_amdgcn_s_setprio(1);
    #pragma unroll
    for (int mm = 0; mm < 4; ++mm)
      #pragma unroll
      for (int nn = 0; nn < 2; ++nn) {
        MFMA16(acc[4 + mm][nn], a1[mm][0], b0[nn][0]);
        MFMA16(acc[4 + mm][nn], a1[mm][1], b0[nn][1]);
      }
    __builtin_amdgcn_s_setprio(0);
    asm volatile("s_waitcnt vmcnt(0) lgkmcnt(0)" ::: "memory");
    __builtin_amdgcn_s_barrier();
    __builtin_amdgcn_sched_barrier(0);
  };

  for (int kt = kt0; kt < ktEnd; kt += 2) {
    tile_body(kt, 0, 32768);
    tile_body(kt + 1, 32768, 0);
  }

  __hip_bfloat16* pz = (z == 0) ? p0 : (z == 1) ? p1 : p2;
  #pragma unroll
  for (int mm = 0; mm < 8; ++mm)
    #pragma unroll
    for (int nn = 0; nn < 4; ++nn)
      #pragma unroll
      for (int r = 0; r < 4; ++r) {
        const int m = m0 + wr * 128 + mm * 16 + g * 4 + r;
        const int n = n0 + wc * 64 + nn * 16 + r16;
        if (z == 3) out[(size_t)m * 1024 + n] = acc[mm][nn][r];
        else        pz[(size_t)m * 1024 + n] = __float2bfloat16(acc[mm][nn][r]);
      }
}

// ---------------- reduce: out = out + p0 + p1 + p2 + res
__global__ __launch_bounds__(256) void reduce_k(const __hip_bfloat16* __restrict__ p0,
                                                const __hip_bfloat16* __restrict__ p1,
                                                const __hip_bfloat16* __restrict__ p2,
                                                const float* __restrict__ res,
                                                float* __restrict__ out) {
  const size_t i4 = (size_t)blockIdx.x * 256 + threadIdx.x;
  float4 o = ((const float4*)out)[i4];
  const float4 rr = ((const float4*)res)[i4];
  const ushort4 a0 = ((const ushort4*)p0)[i4];
  const ushort4 a1 = ((const ushort4*)p1)[i4];
  const ushort4 a2 = ((const ushort4*)p2)[i4];
  o.x += rr.x + bf2f(a0.x) + bf2f(a1.x) + bf2f(a2.x);
  o.y += rr.y + bf2f(a0.y) + bf2f(a1.y) + bf2f(a2.y);
  o.z += rr.z + bf2f(a0.z) + bf2f(a1.z) + bf2f(a2.z);
  o.w += rr.w + bf2f(a0.w) + bf2f(a1.w) + bf2f(a2.w);
  ((float4*)out)[i4] = o;
}

extern "C" void kernel_launch(void* const* d_in, const int* in_sizes, int n_in,
                              void* d_out, int out_size, void* d_ws, size_t ws_size,
                              hipStream_t stream) {
  (void)in_sizes; (void)n_in; (void)out_size; (void)ws_size;
  const float* x      = (const float*)d_in[0];
  const float* in_cb  = (const float*)d_in[1];
  const int*   in_idx = (const int*)d_in[2];
  const float* out_cb = (const float*)d_in[3];
  const int*   out_idx= (const int*)d_in[4];
  float* out = (float*)d_out;
  char* ws = (char*)d_ws;

  __hip_bfloat16* Win  = (__hip_bfloat16*)(ws);                 // 14,680,064
  __hip_bfloat16* Weff = (__hip_bfloat16*)(ws + 14680064);      // 10,485,760
  __hip_bfloat16* xn   = (__hip_bfloat16*)(ws + 25165824);      //  8,388,608
  __hip_bfloat16* h    = (__hip_bfloat16*)(ws + 33554432);      // 58,720,256
  __hip_bfloat16* vT   = (__hip_bfloat16*)(ws + 92274688);      //  8,388,608
  __hip_bfloat16* xa   = (__hip_bfloat16*)(ws + 100663296);     //  8,388,608

  __hip_bfloat16* pk0 = Win;   // dead after gemm1
  __hip_bfloat16* pk1 = xn;    // dead after gemm1
  __hip_bfloat16* pk2 = vT;    // dead after attn

  decode_win_k<<<dim3(7168), dim3(256), 0, stream>>>(in_cb, in_idx, Win);
  decode_weff_k<<<dim3(1024), dim3(256), 0, stream>>>(out_cb, out_idx, Weff);
  ln_k<<<dim3(4096), dim3(256), 0, stream>>>(x, xn);
  gemm1_k<<<dim3(448), dim3(512), 0, stream>>>(xn, Win, h, vT);
  attn_k<<<dim3(16, 16, 4), dim3(256), 0, stream>>>(h, vT, xa);
  gemm2_k<<<dim3(64, 4), dim3(512), 0, stream>>>(h, xa, Weff, pk0, pk1, pk2, out);
  reduce_k<<<dim3(4096), dim3(256), 0, stream>>>(pk0, pk1, pk2, x, out);
}